// Round 13
// baseline (1182.956 us; speedup 1.0000x reference)
//
#include <hip/hip_runtime.h>

// 3x3 SAME conv + bias + ReLU, N=32, Cin=Cout=256, H=W=56, fp32 in/out.
// v13 = v11 + wave anti-phasing:
//  - Block 256co x 256px, 512 thr / 8 waves (2M x 4N), wave tile 128x64
//    (8m x 4n frags of 16x16x32), acc 128 regs.
//  - LDS 2 x (A 32KB + B 32KB) = 128KB, 1 block/CU.
//  - Per K-tile: [vmcnt(0); s_barrier], issue next tile's 8 DMAs, then the
//    4 sub-phases (ks x m-half) in PER-WAVE order: ks-order = (wave>>2)&1,
//    m-half-order = wave&1 -> at any instant ~half the waves read LDS while
//    the other half MFMA (breaks barrier lockstep; v11/v12 alternated).
//  - One sched_barrier(0) mid-tile stops hoisting the 2nd k-half's reads.
//  - x pre-transformed NHWC bf16; w repacked [co][tap*256+ci] bf16;
//    zero-page halo; v7-verified XOR swizzle; XCD-chunked block swizzle.

#define GLOBAL_AS __attribute__((address_space(1)))
#define LDS_AS __attribute__((address_space(3)))

typedef __attribute__((ext_vector_type(8))) short short8;
typedef __attribute__((ext_vector_type(4))) float f32x4;
typedef __attribute__((ext_vector_type(4))) unsigned int u32x4;

#define CIN   256
#define HWS   3136        // 56*56
#define PTOT  100352      // 32*3136
#define KTOT  2304        // CIN*9
#define WROWB 4608        // KTOT*2 bytes per weight row
#define ZPOFF 1179648     // 512B zero page
#define XTOFF 1310720     // x_t: PTOT*512 bytes
#define WSNEED (XTOFF + (size_t)PTOT * 512)

template <int V> struct Int { static constexpr int value = V; };

__device__ __forceinline__ unsigned short f2bf(float f) {
  unsigned u = __builtin_bit_cast(unsigned, f);
  return (unsigned short)((u + 0x7fffu + ((u >> 16) & 1u)) >> 16);  // RNE
}

// Weights OIHW fp32 -> bf16 [co][tap*256+ci]; also zero the zero-page.
__global__ void wcvt_kernel(const float* __restrict__ w, unsigned char* __restrict__ ws) {
  if (blockIdx.x == 0 && threadIdx.x < 128)
    ((unsigned*)(ws + ZPOFF))[threadIdx.x] = 0u;
  int o = blockIdx.x * 256 + threadIdx.x;
  int co = o / KTOT;
  int rr = o - co * KTOT;
  int tap = rr >> 8;
  int ci = rr & 255;
  ((unsigned short*)ws)[o] = f2bf(w[co * KTOT + ci * 9 + tap]);
}

// x NCHW fp32 -> x_t [pix_global][256ci] bf16 (NHWC), via LDS transpose.
__global__ __launch_bounds__(256) void xcvt_kernel(const float* __restrict__ x,
                                                   unsigned char* __restrict__ ws) {
  __shared__ float lt[64 * 257];
  const int pg0 = blockIdx.x * 64;       // 64-px tile, never crosses images
  const int n   = pg0 / HWS;
  const int pi0 = pg0 - n * HWS;
  const int t   = threadIdx.x;
  {
    const int px = t & 63;
    const int cg = t >> 6;               // 0..3 (wave-uniform)
    const float* xb = x + ((size_t)n * 256) * HWS + pi0 + px;
#pragma unroll 8
    for (int i = 0; i < 64; ++i) {
      const int c = i * 4 + cg;
      lt[px * 257 + c] = xb[(size_t)c * HWS];
    }
  }
  __syncthreads();
  {
    const int slot = t & 31;             // 16B slot = 8 channels (32 slots/row)
    const int pxw  = t >> 5;             // 0..7
    unsigned char* xt = ws + XTOFF;
#pragma unroll
    for (int i = 0; i < 8; ++i) {
      const int p = i * 8 + pxw;
      const float* r = &lt[p * 257 + slot * 8];
      u32x4 v;
#pragma unroll
      for (int j = 0; j < 4; ++j)
        v[j] = (unsigned)f2bf(r[2 * j]) | ((unsigned)f2bf(r[2 * j + 1]) << 16);
      *(u32x4*)(xt + (size_t)(pg0 + p) * 512 + slot * 16) = v;
    }
  }
}

__global__ __launch_bounds__(512, 2) void conv_kernel(
    const unsigned char* __restrict__ ws, const float* __restrict__ bias,
    float* __restrict__ out) {
  // LDS: buf{0,1} x (A 32KB + B 32KB)
  __shared__ __align__(16) unsigned char smem[131072];

  const unsigned char* wb = ws;
  const unsigned char* xt = ws + XTOFF;
  const unsigned char* zp = ws + ZPOFF;

  const int bid = blockIdx.x;
  const int sw  = (bid & 7) * 49 + (bid >> 3);   // XCD-chunked, bijective (392=8*49)
  const int p0  = sw * 256;                      // global pixel base

  const int t    = threadIdx.x;
  const int lane = t & 63;
  const int wave = t >> 6;     // 0..7
  const int wm   = wave & 1;   // co half (128 rows)
  const int wn   = wave >> 1;  // px quarter (64 cols)
  const int rl   = lane & 15;
  const int kq   = lane >> 4;
  const int l7   = lane & 7;

  // ---- staging lane precompute: row = op*64 + (t>>3), slot = t&7 ----
  const int srow = t >> 3;                          // 0..63
  const unsigned swzs = (unsigned)(((t & 7) * 16) ^ ((srow & 7) << 4));
  const unsigned ldsW = (unsigned)(wave * 1024);    // wave-uniform chunk

  const unsigned char* aG[4];
  long long bG[4];
  int hB[4], wBp[4];
#pragma unroll
  for (int op = 0; op < 4; ++op) {
    const int arow = op * 64 + srow;                // co row 0..255
    aG[op] = wb + (size_t)arow * WROWB + swzs;
    const int pg = p0 + op * 64 + srow;             // px row 0..255
    const int n  = pg / HWS;
    const int pi = pg - n * HWS;
    hB[op]  = pi / 56;
    wBp[op] = pi - hB[op] * 56;
    bG[op]  = (long long)pg * 512 + (long long)swzs;
  }

  f32x4 acc[8][4];
  const f32x4 zero4 = {0.f, 0.f, 0.f, 0.f};
#pragma unroll
  for (int mi = 0; mi < 8; ++mi)
#pragma unroll
    for (int ni = 0; ni < 4; ++ni) acc[mi][ni] = zero4;

  auto stageA = [&](int cq, int tap, int buf) {
    const unsigned koffA = (unsigned)(tap * 512 + cq * 128);
    unsigned char* lb = smem + buf * 65536;
#pragma unroll
    for (int op = 0; op < 4; ++op)
      __builtin_amdgcn_global_load_lds(
          (const GLOBAL_AS unsigned int*)(aG[op] + koffA),
          (LDS_AS unsigned int*)(lb + op * 8192 + ldsW), 16, 0, 0);
  };
  auto stageB = [&](int cq, int tap, int buf) {
    const int kh = tap / 3;
    const int dh = kh - 1;
    const int dw = (tap - kh * 3) - 1;
    unsigned char* lb = smem + buf * 65536;
    const long long doff = (long long)(dh * 56 + dw) * 512 + cq * 128;
#pragma unroll
    for (int op = 0; op < 4; ++op) {
      const int hh  = hB[op] + dh;
      const int wwi = wBp[op] + dw;
      const bool ok = ((unsigned)hh < 56u) && ((unsigned)wwi < 56u);
      const unsigned char* g = ok ? (xt + bG[op] + doff) : zp;
      __builtin_amdgcn_global_load_lds(
          (const GLOBAL_AS unsigned int*)g,
          (LDS_AS unsigned int*)(lb + 32768 + op * 8192 + ldsW), 16, 0, 0);
    }
  };

  // compute-phase per-lane offsets (128B rows, read XOR = store XOR)
  unsigned koff[2];
  koff[0] = (unsigned)((kq * 16) ^ (l7 << 4));
  koff[1] = (unsigned)((kq * 16 + 64) ^ (l7 << 4));
  unsigned offAm[8], offBn[4];
#pragma unroll
  for (int mi = 0; mi < 8; ++mi)
    offAm[mi] = (unsigned)((wm * 128 + mi * 16 + rl) * 128);
#pragma unroll
  for (int ni = 0; ni < 4; ++ni)
    offBn[ni] = (unsigned)((wn * 64 + ni * 16 + rl) * 128);

  // per-wave traversal order (anti-phasing): SIMD-mates differ in ks order
  const int ksel = __builtin_amdgcn_readfirstlane((wave >> 2) & 1);
  const int msel = __builtin_amdgcn_readfirstlane(wave & 1);
  const unsigned kFirst  = ksel ? koff[1] : koff[0];
  const unsigned kSecond = ksel ? koff[0] : koff[1];

  // one K-tile's compute, m-half order MO0 then MO0^4, k order kf then ks_
  auto tileBody = [&](const unsigned char* bA, const unsigned char* bB,
                      unsigned kf, unsigned ks_, auto moTag) {
    constexpr int MO0 = decltype(moTag)::value;
    constexpr int MO1 = MO0 ^ 4;
    short8 av[4], bv[4];
    // ---- k-half 1, m-half 1 ----
#pragma unroll
    for (int ni = 0; ni < 4; ++ni)
      bv[ni] = *(const short8*)(bB + offBn[ni] + kf);
#pragma unroll
    for (int mi = 0; mi < 4; ++mi)
      av[mi] = *(const short8*)(bA + offAm[mi + MO0] + kf);
    __builtin_amdgcn_s_setprio(1);
#pragma unroll
    for (int mi = 0; mi < 4; ++mi)
#pragma unroll
      for (int ni = 0; ni < 4; ++ni)
        acc[mi + MO0][ni] = __builtin_amdgcn_mfma_f32_16x16x32_bf16(
            av[mi], bv[ni], acc[mi + MO0][ni], 0, 0, 0);
    __builtin_amdgcn_s_setprio(0);
    // ---- k-half 1, m-half 2 (B reg-reused) ----
#pragma unroll
    for (int mi = 0; mi < 4; ++mi)
      av[mi] = *(const short8*)(bA + offAm[mi + MO1] + kf);
    __builtin_amdgcn_s_setprio(1);
#pragma unroll
    for (int mi = 0; mi < 4; ++mi)
#pragma unroll
      for (int ni = 0; ni < 4; ++ni)
        acc[mi + MO1][ni] = __builtin_amdgcn_mfma_f32_16x16x32_bf16(
            av[mi], bv[ni], acc[mi + MO1][ni], 0, 0, 0);
    __builtin_amdgcn_s_setprio(0);
    // keep 2nd k-half's reads from hoisting into the 1st burst
    __builtin_amdgcn_sched_barrier(0);
    // ---- k-half 2, m-half 1 ----
#pragma unroll
    for (int ni = 0; ni < 4; ++ni)
      bv[ni] = *(const short8*)(bB + offBn[ni] + ks_);
#pragma unroll
    for (int mi = 0; mi < 4; ++mi)
      av[mi] = *(const short8*)(bA + offAm[mi + MO0] + ks_);
    __builtin_amdgcn_s_setprio(1);
#pragma unroll
    for (int mi = 0; mi < 4; ++mi)
#pragma unroll
      for (int ni = 0; ni < 4; ++ni)
        acc[mi + MO0][ni] = __builtin_amdgcn_mfma_f32_16x16x32_bf16(
            av[mi], bv[ni], acc[mi + MO0][ni], 0, 0, 0);
    __builtin_amdgcn_s_setprio(0);
    // ---- k-half 2, m-half 2 ----
#pragma unroll
    for (int mi = 0; mi < 4; ++mi)
      av[mi] = *(const short8*)(bA + offAm[mi + MO1] + ks_);
    __builtin_amdgcn_s_setprio(1);
#pragma unroll
    for (int mi = 0; mi < 4; ++mi)
#pragma unroll
      for (int ni = 0; ni < 4; ++ni)
        acc[mi + MO1][ni] = __builtin_amdgcn_mfma_f32_16x16x32_bf16(
            av[mi], bv[ni], acc[mi + MO1][ni], 0, 0, 0);
    __builtin_amdgcn_s_setprio(0);
  };

  // ---- prologue: stage tile 0 into buf0 ----
  stageA(0, 0, 0);
  stageB(0, 0, 0);

  int buf = 0;
#pragma unroll 1
  for (int s = 0; s < 36; ++s) {
    // tile entry: wait own stage ops, then rendezvous (no drain of new ops)
    asm volatile("s_waitcnt vmcnt(0)\n\ts_barrier" ::: "memory");
    // issue next tile's 8 DMA ops - they stay in flight across this tile
    if (s + 1 < 36) {
      const int s1   = s + 1;
      const int ncq  = s1 / 9;
      const int ntap = s1 - ncq * 9;
      stageA(ncq, ntap, buf ^ 1);
      stageB(ncq, ntap, buf ^ 1);
    }
    const unsigned char* bA = smem + buf * 65536;
    const unsigned char* bB = bA + 32768;
    if (msel) tileBody(bA, bB, kFirst, kSecond, Int<4>{});
    else      tileBody(bA, bB, kFirst, kSecond, Int<0>{});
    buf ^= 1;
  }

  // ---- epilogue: bias + ReLU. C/D: col=lane&15, row=(lane>>4)*4+j ----
#pragma unroll
  for (int mi = 0; mi < 8; ++mi) {
    const int row = wm * 128 + mi * 16 + kq * 4;
    float br[4];
#pragma unroll
    for (int j = 0; j < 4; ++j) br[j] = bias[row + j];
#pragma unroll
    for (int ni = 0; ni < 4; ++ni) {
      const int pgb = p0 + wn * 64 + ni * 16;     // 16-span within one image
      const int n   = pgb / HWS;
      const int pib = pgb - n * HWS;
#pragma unroll
      for (int j = 0; j < 4; ++j) {
        float v = acc[mi][ni][j] + br[j];
        out[(size_t)(n * 256 + row + j) * HWS + pib + rl] = fmaxf(v, 0.f);
      }
    }
  }
}

// Correct-but-slow fallback if workspace is too small (not expected).
__global__ void naive_kernel(const float* __restrict__ x, const float* __restrict__ w,
                             const float* __restrict__ bias, float* __restrict__ out) {
  int idx = blockIdx.x * 256 + threadIdx.x;
  if (idx >= 32 * 256 * HWS) return;
  int n  = idx / (256 * HWS);
  int r  = idx - n * 256 * HWS;
  int co = r / HWS;
  int p  = r - co * HWS;
  int h = p / 56, ww = p - h * 56;
  float s = bias[co];
  const float* xb = x + (size_t)n * 256 * HWS;
  const float* wbp = w + (size_t)co * KTOT;
  for (int ci = 0; ci < 256; ++ci) {
    const float* xc = xb + (size_t)ci * HWS;
    const float* wc = wbp + ci * 9;
    for (int kh = 0; kh < 3; ++kh) {
      int hh = h + kh - 1;
      if ((unsigned)hh >= 56u) continue;
      for (int kw = 0; kw < 3; ++kw) {
        int w2 = ww + kw - 1;
        if ((unsigned)w2 >= 56u) continue;
        s += xc[hh * 56 + w2] * wc[kh * 3 + kw];
      }
    }
  }
  out[idx] = fmaxf(s, 0.f);
}

extern "C" void kernel_launch(void* const* d_in, const int* in_sizes, int n_in,
                              void* d_out, int out_size, void* d_ws, size_t ws_size,
                              hipStream_t stream) {
  const float* x    = (const float*)d_in[0];
  const float* w    = (const float*)d_in[1];
  const float* bias = (const float*)d_in[2];
  float* out        = (float*)d_out;

  if (ws_size < WSNEED) {
    hipLaunchKernelGGL(naive_kernel, dim3((32 * 256 * HWS + 255) / 256), dim3(256),
                       0, stream, x, w, bias, out);
    return;
  }
  unsigned char* ws = (unsigned char*)d_ws;
  hipLaunchKernelGGL(wcvt_kernel, dim3(2304), dim3(256), 0, stream, w, ws);
  hipLaunchKernelGGL(xcvt_kernel, dim3(PTOT / 64), dim3(256), 0, stream, x, ws);
  hipLaunchKernelGGL(conv_kernel, dim3(392), dim3(512), 0, stream, ws, bias, out);
}

// Round 14
// 183.451 us; speedup vs baseline: 6.4483x; 6.4483x over previous
//
#include <hip/hip_runtime.h>

// 3x3 SAME conv + bias + ReLU, N=32, Cin=Cout=256, H=W=56, fp32 in/out.
// v14 = v7 geometry with BK=32 and 3 co-resident blocks/CU:
//  - BM=128co x BN=128px, 4 waves, wave tile 64x64 (acc 64 regs).
//  - BK=32 -> LDS buffer 16KB (A 8 + B 8), dbuf 32KB/block.
//  - __launch_bounds__(256,3): <=170 VGPR -> 12 waves/CU -> THREE
//    independent blocks co-resident (m114 cross-block overlap: the only
//    mechanism that breaks the barrier-lockstep read/MFMA alternation).
//  - 72 K-steps, 2-phase dbuf, one __syncthreads per step (v7-proven).
//  - 64B LDS rows: chunk XOR = row&3 (2-way bank alias max = free).
//  - x pre-transformed NHWC bf16; w repacked [co][tap*256+ci] bf16;
//    zero-page halo; XCD-chunked block swizzle (1568 = 8*196).

#define GLOBAL_AS __attribute__((address_space(1)))
#define LDS_AS __attribute__((address_space(3)))

typedef __attribute__((ext_vector_type(8))) short short8;
typedef __attribute__((ext_vector_type(4))) float f32x4;
typedef __attribute__((ext_vector_type(4))) unsigned int u32x4;

#define CIN   256
#define HWS   3136        // 56*56
#define PTOT  100352      // 32*3136
#define KTOT  2304        // CIN*9
#define WROWB 4608        // KTOT*2 bytes per weight row
#define ZPOFF 1179648     // 512B zero page
#define XTOFF 1310720     // x_t: PTOT*512 bytes
#define WSNEED (XTOFF + (size_t)PTOT * 512)

__device__ __forceinline__ unsigned short f2bf(float f) {
  unsigned u = __builtin_bit_cast(unsigned, f);
  return (unsigned short)((u + 0x7fffu + ((u >> 16) & 1u)) >> 16);  // RNE
}

// Weights OIHW fp32 -> bf16 [co][tap*256+ci]; also zero the zero-page.
__global__ void wcvt_kernel(const float* __restrict__ w, unsigned char* __restrict__ ws) {
  if (blockIdx.x == 0 && threadIdx.x < 128)
    ((unsigned*)(ws + ZPOFF))[threadIdx.x] = 0u;
  int o = blockIdx.x * 256 + threadIdx.x;
  int co = o / KTOT;
  int rr = o - co * KTOT;
  int tap = rr >> 8;
  int ci = rr & 255;
  ((unsigned short*)ws)[o] = f2bf(w[co * KTOT + ci * 9 + tap]);
}

// x NCHW fp32 -> x_t [pix_global][256ci] bf16 (NHWC), via LDS transpose.
__global__ __launch_bounds__(256) void xcvt_kernel(const float* __restrict__ x,
                                                   unsigned char* __restrict__ ws) {
  __shared__ float lt[64 * 257];
  const int pg0 = blockIdx.x * 64;       // 64-px tile, never crosses images
  const int n   = pg0 / HWS;
  const int pi0 = pg0 - n * HWS;
  const int t   = threadIdx.x;
  {
    const int px = t & 63;
    const int cg = t >> 6;               // 0..3 (wave-uniform)
    const float* xb = x + ((size_t)n * 256) * HWS + pi0 + px;
#pragma unroll 8
    for (int i = 0; i < 64; ++i) {
      const int c = i * 4 + cg;
      lt[px * 257 + c] = xb[(size_t)c * HWS];
    }
  }
  __syncthreads();
  {
    const int slot = t & 31;             // 16B slot = 8 channels (32 slots/row)
    const int pxw  = t >> 5;             // 0..7
    unsigned char* xt = ws + XTOFF;
#pragma unroll
    for (int i = 0; i < 8; ++i) {
      const int p = i * 8 + pxw;
      const float* r = &lt[p * 257 + slot * 8];
      u32x4 v;
#pragma unroll
      for (int j = 0; j < 4; ++j)
        v[j] = (unsigned)f2bf(r[2 * j]) | ((unsigned)f2bf(r[2 * j + 1]) << 16);
      *(u32x4*)(xt + (size_t)(pg0 + p) * 512 + slot * 16) = v;
    }
  }
}

__global__ __launch_bounds__(256, 3) void conv_kernel(
    const unsigned char* __restrict__ ws, const float* __restrict__ bias,
    float* __restrict__ out) {
  // LDS: buf{0,1} x (A 8KB + B 8KB) = 32KB
  __shared__ __align__(16) unsigned char smem[32768];

  const unsigned char* wb = ws;
  const unsigned char* xt = ws + XTOFF;
  const unsigned char* zp = ws + ZPOFF;

  const int bid = blockIdx.x;
  const int sw  = (bid & 7) * 196 + (bid >> 3);  // XCD-chunked, bijective (1568=8*196)
  const int co0 = (sw & 1) * 128;
  const int p0  = (sw >> 1) * 128;               // global pixel base

  const int t    = threadIdx.x;
  const int lane = t & 63;
  const int wave = t >> 6;     // 0..3
  const int wm   = wave & 1;   // co 64-half
  const int wn   = wave >> 1;  // px 64-half
  const int rl   = lane & 15;
  const int kq   = lane >> 4;

  // ---- staging lane precompute: 64B rows, 4 lanes/row, chunk XOR row&3 ----
  const int srow = t >> 2;                           // 0..63 (row within op)
  const unsigned swzs = (unsigned)((((t & 3) ^ (srow & 3)) << 4));

  const unsigned char* aG[2];
  long long bG[2];
  int hB[2], wBp[2];
#pragma unroll
  for (int op = 0; op < 2; ++op) {
    const int row = op * 64 + srow;                  // 0..127
    aG[op] = wb + (size_t)(co0 + row) * WROWB + swzs;
    const int pg = p0 + row;
    const int n  = pg / HWS;
    const int pi = pg - n * HWS;
    hB[op]  = pi / 56;
    wBp[op] = pi - hB[op] * 56;
    bG[op]  = (long long)pg * 512 + (long long)swzs;
  }

  f32x4 acc[4][4];
  const f32x4 zero4 = {0.f, 0.f, 0.f, 0.f};
#pragma unroll
  for (int mi = 0; mi < 4; ++mi)
#pragma unroll
    for (int ni = 0; ni < 4; ++ni) acc[mi][ni] = zero4;

  // K-step s (0..71): cq = s/18, r = s%18, tap = r>>1, khalf = r&1
  auto stage = [&](int s, int buf) {
    const int cq  = s / 18;
    const int r   = s - cq * 18;
    const int tap = r >> 1;
    const int kh2 = r & 1;
    const int kh  = tap / 3;
    const int dh  = kh - 1;
    const int dw  = (tap - kh * 3) - 1;
    const unsigned koffA = (unsigned)(tap * 512 + cq * 128 + kh2 * 64);
    unsigned char* lb = smem + buf * 16384;
#pragma unroll
    for (int op = 0; op < 2; ++op)
      __builtin_amdgcn_global_load_lds(
          (const GLOBAL_AS unsigned int*)(aG[op] + koffA),
          (LDS_AS unsigned int*)(lb + op * 4096 + (t >> 6) * 1024), 16, 0, 0);
    const long long doff = (long long)(dh * 56 + dw) * 512 + cq * 128 + kh2 * 64;
#pragma unroll
    for (int op = 0; op < 2; ++op) {
      const int hh  = hB[op] + dh;
      const int wwi = wBp[op] + dw;
      const bool ok = ((unsigned)hh < 56u) && ((unsigned)wwi < 56u);
      const unsigned char* g = ok ? (xt + bG[op] + doff) : zp;
      __builtin_amdgcn_global_load_lds(
          (const GLOBAL_AS unsigned int*)g,
          (LDS_AS unsigned int*)(lb + 8192 + op * 4096 + (t >> 6) * 1024), 16, 0, 0);
    }
  };

  // compute-phase per-lane offsets (64B rows; read XOR = store XOR, row&3=rl&3)
  const unsigned krd = (unsigned)((kq * 16) ^ ((rl & 3) << 4));
  unsigned offA[4], offB[4];
#pragma unroll
  for (int i = 0; i < 4; ++i) {
    offA[i] = (unsigned)((wm * 64 + i * 16 + rl) * 64) + krd;
    offB[i] = (unsigned)((wn * 64 + i * 16 + rl) * 64) + krd;
  }

  auto compute = [&](int buf) {
    const unsigned char* bA = smem + buf * 16384;
    const unsigned char* bB = bA + 8192;
    short8 av[4], bv[4];
#pragma unroll
    for (int mi = 0; mi < 4; ++mi)
      av[mi] = *(const short8*)(bA + offA[mi]);
#pragma unroll
    for (int ni = 0; ni < 4; ++ni)
      bv[ni] = *(const short8*)(bB + offB[ni]);
#pragma unroll
    for (int mi = 0; mi < 4; ++mi)
#pragma unroll
      for (int ni = 0; ni < 4; ++ni)
        acc[mi][ni] = __builtin_amdgcn_mfma_f32_16x16x32_bf16(
            av[mi], bv[ni], acc[mi][ni], 0, 0, 0);
  };

  // ---- 2-phase pipeline over 72 K-steps ----
  stage(0, 0);
  __syncthreads();
  int buf = 0;
#pragma unroll 1
  for (int s = 0; s < 72; ++s) {
    if (s < 71) stage(s + 1, buf ^ 1);
    compute(buf);
    __syncthreads();
    buf ^= 1;
  }

  // ---- epilogue: bias + ReLU. C/D: col=lane&15, row=(lane>>4)*4+j ----
#pragma unroll
  for (int mi = 0; mi < 4; ++mi) {
    const int row = co0 + wm * 64 + mi * 16 + kq * 4;
    float br[4];
#pragma unroll
    for (int j = 0; j < 4; ++j) br[j] = bias[row + j];
#pragma unroll
    for (int ni = 0; ni < 4; ++ni) {
      const int pgb = p0 + wn * 64 + ni * 16;     // 16-span within one image
      const int n   = pgb / HWS;
      const int pib = pgb - n * HWS;
#pragma unroll
      for (int j = 0; j < 4; ++j) {
        float v = acc[mi][ni][j] + br[j];
        out[(size_t)(n * 256 + row + j) * HWS + pib + rl] = fmaxf(v, 0.f);
      }
    }
  }
}

// Correct-but-slow fallback if workspace is too small (not expected).
__global__ void naive_kernel(const float* __restrict__ x, const float* __restrict__ w,
                             const float* __restrict__ bias, float* __restrict__ out) {
  int idx = blockIdx.x * 256 + threadIdx.x;
  if (idx >= 32 * 256 * HWS) return;
  int n  = idx / (256 * HWS);
  int r  = idx - n * 256 * HWS;
  int co = r / HWS;
  int p  = r - co * HWS;
  int h = p / 56, ww = p - h * 56;
  float s = bias[co];
  const float* xb = x + (size_t)n * 256 * HWS;
  const float* wbp = w + (size_t)co * KTOT;
  for (int ci = 0; ci < 256; ++ci) {
    const float* xc = xb + (size_t)ci * HWS;
    const float* wc = wbp + ci * 9;
    for (int kh = 0; kh < 3; ++kh) {
      int hh = h + kh - 1;
      if ((unsigned)hh >= 56u) continue;
      for (int kw = 0; kw < 3; ++kw) {
        int w2 = ww + kw - 1;
        if ((unsigned)w2 >= 56u) continue;
        s += xc[hh * 56 + w2] * wc[kh * 3 + kw];
      }
    }
  }
  out[idx] = fmaxf(s, 0.f);
}

extern "C" void kernel_launch(void* const* d_in, const int* in_sizes, int n_in,
                              void* d_out, int out_size, void* d_ws, size_t ws_size,
                              hipStream_t stream) {
  const float* x    = (const float*)d_in[0];
  const float* w    = (const float*)d_in[1];
  const float* bias = (const float*)d_in[2];
  float* out        = (float*)d_out;

  if (ws_size < WSNEED) {
    hipLaunchKernelGGL(naive_kernel, dim3((32 * 256 * HWS + 255) / 256), dim3(256),
                       0, stream, x, w, bias, out);
    return;
  }
  unsigned char* ws = (unsigned char*)d_ws;
  hipLaunchKernelGGL(wcvt_kernel, dim3(2304), dim3(256), 0, stream, w, ws);
  hipLaunchKernelGGL(xcvt_kernel, dim3(PTOT / 64), dim3(256), 0, stream, x, ws);
  hipLaunchKernelGGL(conv_kernel, dim3(1568), dim3(256), 0, stream, ws, bias, out);
}

// Round 15
// 180.586 us; speedup vs baseline: 6.5506x; 1.0159x over previous
//
#include <hip/hip_runtime.h>

// 3x3 SAME conv + bias + ReLU, N=32, Cin=Cout=256, H=W=56, fp32 in/out.
// v15 = v14 + conflict-free 64B-row swizzle + 4 blocks/CU:
//  - BM=128co x BN=128px, 4 waves, wave tile 64x64 (acc 64 regs).
//  - BK=32 -> LDS buffer 16KB (A 8 + B 8), dbuf 32KB/block.
//  - __launch_bounds__(256,4): 16 waves/CU -> FOUR independent blocks
//    co-resident (m114 cross-block overlap breaks read/MFMA lockstep).
//  - 64B rows: chunk XOR = (row>>1)&3  [v14's (row&3) collided within
//    8-lane b128 beats -> 14.4M conflicts; this maps each 8-lane group
//    to 8 distinct 16B slots -> 0 conflicts].
//  - 72 K-steps, 2-phase dbuf, one __syncthreads per step.
//  - x pre-transformed NHWC bf16; w repacked [co][tap*256+ci] bf16;
//    zero-page halo; XCD-chunked block swizzle (1568 = 8*196).

#define GLOBAL_AS __attribute__((address_space(1)))
#define LDS_AS __attribute__((address_space(3)))

typedef __attribute__((ext_vector_type(8))) short short8;
typedef __attribute__((ext_vector_type(4))) float f32x4;
typedef __attribute__((ext_vector_type(4))) unsigned int u32x4;

#define CIN   256
#define HWS   3136        // 56*56
#define PTOT  100352      // 32*3136
#define KTOT  2304        // CIN*9
#define WROWB 4608        // KTOT*2 bytes per weight row
#define ZPOFF 1179648     // 512B zero page
#define XTOFF 1310720     // x_t: PTOT*512 bytes
#define WSNEED (XTOFF + (size_t)PTOT * 512)

__device__ __forceinline__ unsigned short f2bf(float f) {
  unsigned u = __builtin_bit_cast(unsigned, f);
  return (unsigned short)((u + 0x7fffu + ((u >> 16) & 1u)) >> 16);  // RNE
}

// Weights OIHW fp32 -> bf16 [co][tap*256+ci]; also zero the zero-page.
__global__ void wcvt_kernel(const float* __restrict__ w, unsigned char* __restrict__ ws) {
  if (blockIdx.x == 0 && threadIdx.x < 128)
    ((unsigned*)(ws + ZPOFF))[threadIdx.x] = 0u;
  int o = blockIdx.x * 256 + threadIdx.x;
  int co = o / KTOT;
  int rr = o - co * KTOT;
  int tap = rr >> 8;
  int ci = rr & 255;
  ((unsigned short*)ws)[o] = f2bf(w[co * KTOT + ci * 9 + tap]);
}

// x NCHW fp32 -> x_t [pix_global][256ci] bf16 (NHWC), via LDS transpose.
__global__ __launch_bounds__(256) void xcvt_kernel(const float* __restrict__ x,
                                                   unsigned char* __restrict__ ws) {
  __shared__ float lt[64 * 257];
  const int pg0 = blockIdx.x * 64;       // 64-px tile, never crosses images
  const int n   = pg0 / HWS;
  const int pi0 = pg0 - n * HWS;
  const int t   = threadIdx.x;
  {
    const int px = t & 63;
    const int cg = t >> 6;               // 0..3 (wave-uniform)
    const float* xb = x + ((size_t)n * 256) * HWS + pi0 + px;
#pragma unroll 8
    for (int i = 0; i < 64; ++i) {
      const int c = i * 4 + cg;
      lt[px * 257 + c] = xb[(size_t)c * HWS];
    }
  }
  __syncthreads();
  {
    const int slot = t & 31;             // 16B slot = 8 channels (32 slots/row)
    const int pxw  = t >> 5;             // 0..7
    unsigned char* xt = ws + XTOFF;
#pragma unroll
    for (int i = 0; i < 8; ++i) {
      const int p = i * 8 + pxw;
      const float* r = &lt[p * 257 + slot * 8];
      u32x4 v;
#pragma unroll
      for (int j = 0; j < 4; ++j)
        v[j] = (unsigned)f2bf(r[2 * j]) | ((unsigned)f2bf(r[2 * j + 1]) << 16);
      *(u32x4*)(xt + (size_t)(pg0 + p) * 512 + slot * 16) = v;
    }
  }
}

__global__ __launch_bounds__(256, 4) void conv_kernel(
    const unsigned char* __restrict__ ws, const float* __restrict__ bias,
    float* __restrict__ out) {
  // LDS: buf{0,1} x (A 8KB + B 8KB) = 32KB
  __shared__ __align__(16) unsigned char smem[32768];

  const unsigned char* wb = ws;
  const unsigned char* xt = ws + XTOFF;
  const unsigned char* zp = ws + ZPOFF;

  const int bid = blockIdx.x;
  const int sw  = (bid & 7) * 196 + (bid >> 3);  // XCD-chunked, bijective (1568=8*196)
  const int co0 = (sw & 1) * 128;
  const int p0  = (sw >> 1) * 128;               // global pixel base

  const int t    = threadIdx.x;
  const int lane = t & 63;
  const int wave = t >> 6;     // 0..3
  const int wm   = wave & 1;   // co 64-half
  const int wn   = wave >> 1;  // px 64-half
  const int rl   = lane & 15;
  const int kq   = lane >> 4;

  // ---- staging lane precompute: 64B rows, 4 lanes/row ----
  // store chunk position (t&3) holds logical chunk (t&3)^((row>>1)&3)
  const int srow = t >> 2;                           // 0..63 (row within op)
  const unsigned swzs = (unsigned)((((t & 3) ^ ((srow >> 1) & 3)) << 4));

  const unsigned char* aG[2];
  long long bG[2];
  int hB[2], wBp[2];
#pragma unroll
  for (int op = 0; op < 2; ++op) {
    const int row = op * 64 + srow;                  // 0..127
    aG[op] = wb + (size_t)(co0 + row) * WROWB + swzs;
    const int pg = p0 + row;
    const int n  = pg / HWS;
    const int pi = pg - n * HWS;
    hB[op]  = pi / 56;
    wBp[op] = pi - hB[op] * 56;
    bG[op]  = (long long)pg * 512 + (long long)swzs;
  }

  f32x4 acc[4][4];
  const f32x4 zero4 = {0.f, 0.f, 0.f, 0.f};
#pragma unroll
  for (int mi = 0; mi < 4; ++mi)
#pragma unroll
    for (int ni = 0; ni < 4; ++ni) acc[mi][ni] = zero4;

  // K-step s (0..71): cq = s/18, r = s%18, tap = r>>1, khalf = r&1
  auto stage = [&](int s, int buf) {
    const int cq  = s / 18;
    const int r   = s - cq * 18;
    const int tap = r >> 1;
    const int kh2 = r & 1;
    const int kh  = tap / 3;
    const int dh  = kh - 1;
    const int dw  = (tap - kh * 3) - 1;
    const unsigned koffA = (unsigned)(tap * 512 + cq * 128 + kh2 * 64);
    unsigned char* lb = smem + buf * 16384;
#pragma unroll
    for (int op = 0; op < 2; ++op)
      __builtin_amdgcn_global_load_lds(
          (const GLOBAL_AS unsigned int*)(aG[op] + koffA),
          (LDS_AS unsigned int*)(lb + op * 4096 + (t >> 6) * 1024), 16, 0, 0);
    const long long doff = (long long)(dh * 56 + dw) * 512 + cq * 128 + kh2 * 64;
#pragma unroll
    for (int op = 0; op < 2; ++op) {
      const int hh  = hB[op] + dh;
      const int wwi = wBp[op] + dw;
      const bool ok = ((unsigned)hh < 56u) && ((unsigned)wwi < 56u);
      const unsigned char* g = ok ? (xt + bG[op] + doff) : zp;
      __builtin_amdgcn_global_load_lds(
          (const GLOBAL_AS unsigned int*)g,
          (LDS_AS unsigned int*)(lb + 8192 + op * 4096 + (t >> 6) * 1024), 16, 0, 0);
    }
  };

  // compute-phase per-lane offsets (64B rows; read XOR = (row>>1)&3, row≡rl)
  const unsigned krd = (unsigned)((kq * 16) ^ (((rl >> 1) & 3) << 4));
  unsigned offA[4], offB[4];
#pragma unroll
  for (int i = 0; i < 4; ++i) {
    offA[i] = (unsigned)((wm * 64 + i * 16 + rl) * 64) + krd;
    offB[i] = (unsigned)((wn * 64 + i * 16 + rl) * 64) + krd;
  }

  auto compute = [&](int buf) {
    const unsigned char* bA = smem + buf * 16384;
    const unsigned char* bB = bA + 8192;
    short8 av[4], bv[4];
#pragma unroll
    for (int mi = 0; mi < 4; ++mi)
      av[mi] = *(const short8*)(bA + offA[mi]);
#pragma unroll
    for (int ni = 0; ni < 4; ++ni)
      bv[ni] = *(const short8*)(bB + offB[ni]);
#pragma unroll
    for (int mi = 0; mi < 4; ++mi)
#pragma unroll
      for (int ni = 0; ni < 4; ++ni)
        acc[mi][ni] = __builtin_amdgcn_mfma_f32_16x16x32_bf16(
            av[mi], bv[ni], acc[mi][ni], 0, 0, 0);
  };

  // ---- 2-phase pipeline over 72 K-steps ----
  stage(0, 0);
  __syncthreads();
  int buf = 0;
#pragma unroll 1
  for (int s = 0; s < 72; ++s) {
    if (s < 71) stage(s + 1, buf ^ 1);
    compute(buf);
    __syncthreads();
    buf ^= 1;
  }

  // ---- epilogue: bias + ReLU. C/D: col=lane&15, row=(lane>>4)*4+j ----
#pragma unroll
  for (int mi = 0; mi < 4; ++mi) {
    const int row = co0 + wm * 64 + mi * 16 + kq * 4;
    float br[4];
#pragma unroll
    for (int j = 0; j < 4; ++j) br[j] = bias[row + j];
#pragma unroll
    for (int ni = 0; ni < 4; ++ni) {
      const int pgb = p0 + wn * 64 + ni * 16;     // 16-span within one image
      const int n   = pgb / HWS;
      const int pib = pgb - n * HWS;
#pragma unroll
      for (int j = 0; j < 4; ++j) {
        float v = acc[mi][ni][j] + br[j];
        out[(size_t)(n * 256 + row + j) * HWS + pib + rl] = fmaxf(v, 0.f);
      }
    }
  }
}

// Correct-but-slow fallback if workspace is too small (not expected).
__global__ void naive_kernel(const float* __restrict__ x, const float* __restrict__ w,
                             const float* __restrict__ bias, float* __restrict__ out) {
  int idx = blockIdx.x * 256 + threadIdx.x;
  if (idx >= 32 * 256 * HWS) return;
  int n  = idx / (256 * HWS);
  int r  = idx - n * 256 * HWS;
  int co = r / HWS;
  int p  = r - co * HWS;
  int h = p / 56, ww = p - h * 56;
  float s = bias[co];
  const float* xb = x + (size_t)n * 256 * HWS;
  const float* wbp = w + (size_t)co * KTOT;
  for (int ci = 0; ci < 256; ++ci) {
    const float* xc = xb + (size_t)ci * HWS;
    const float* wc = wbp + ci * 9;
    for (int kh = 0; kh < 3; ++kh) {
      int hh = h + kh - 1;
      if ((unsigned)hh >= 56u) continue;
      for (int kw = 0; kw < 3; ++kw) {
        int w2 = ww + kw - 1;
        if ((unsigned)w2 >= 56u) continue;
        s += xc[hh * 56 + w2] * wc[kh * 3 + kw];
      }
    }
  }
  out[idx] = fmaxf(s, 0.f);
}

extern "C" void kernel_launch(void* const* d_in, const int* in_sizes, int n_in,
                              void* d_out, int out_size, void* d_ws, size_t ws_size,
                              hipStream_t stream) {
  const float* x    = (const float*)d_in[0];
  const float* w    = (const float*)d_in[1];
  const float* bias = (const float*)d_in[2];
  float* out        = (float*)d_out;

  if (ws_size < WSNEED) {
    hipLaunchKernelGGL(naive_kernel, dim3((32 * 256 * HWS + 255) / 256), dim3(256),
                       0, stream, x, w, bias, out);
    return;
  }
  unsigned char* ws = (unsigned char*)d_ws;
  hipLaunchKernelGGL(wcvt_kernel, dim3(2304), dim3(256), 0, stream, w, ws);
  hipLaunchKernelGGL(xcvt_kernel, dim3(PTOT / 64), dim3(256), 0, stream, x, ws);
  hipLaunchKernelGGL(conv_kernel, dim3(1568), dim3(256), 0, stream, ws, bias, out);
}